// Round 4
// baseline (262.647 us; speedup 1.0000x reference)
//
#include <hip/hip_runtime.h>

// ============================================================================
// ContDecoder on MI355X — bf16 MFMA, round 6.
// MPTS=32, 1024 threads (16 waves), 55.8 KB dynamic LDS, 2 blocks/CU.
//
// Round-5 post-mortem: VGPR=28 — compiler sank the software-pipeline ring;
// real limits are (a) LDS A-read amplification (every n-tile unit re-reads
// the same A-frags: 972 KB/block), (b) 4-way-conflicted scalar u16 epilogue
// stores (62K cyc/CU of bank conflicts), (c) 1-load-deep latency chains.
// Round-6 levers:
//   (1) swapped MFMA operands: mfma(W,X) -> D[n,pt] transposed. Weight and
//       activation frags have identical layouts as A- or B-operand, so the
//       swap is free. Epilogue: 4 consecutive n per lane -> one ds_write_b64
//       (4x fewer stores, no 4-way u16 conflicts); bias via float4.
//   (2) 2m x 8n wave mapping: wave owns 1 m-tile and ceil(NT/8) n-tiles;
//       A-frags loaded once per K-chunk, reused across the wave's n-tiles
//       (L1 A-traffic halves). Duplicate B-reads across the 2 m-groups hit
//       the per-CU L1 cache (same block) -> near-free.
//   (3) K-chunk CK=5: cluster 5 A-reads + 5 B-loads structurally above the
//       5 MFMAs -> ~10 loads amortize one latency exposure.
//
// LDS row layout per point (bf16): [xin 0..64 | hA 64..608 | hB 608..864],
// stride 872 elems. Stale bytes in reused regions are masked by zero-packed
// weight rows; pad neurons get bias 0 so they write exact zeros.
// ============================================================================

#define NTH     1024
#define NWAVES  16
#define MPTS    32              // points per block (2 m-tiles of 16)
#define MTILES  (MPTS / 16)
#define SROW    872             // LDS row stride in bf16 elems
#define XIN_OFF 0
#define HA_OFF  64
#define HB_OFF  608
#define NPOINTS (8 * 16384)
#define GRIDX   (NPOINTS / MPTS)   // 4096 blocks
#define LDSBYTES (MPTS * SROW * 2) // 55808 -> 2 blocks/CU

typedef short          short8 __attribute__((ext_vector_type(8)));
typedef short          short4v __attribute__((ext_vector_type(4)));
typedef float          f32x4  __attribute__((ext_vector_type(4)));
typedef unsigned short u16;

__device__ __forceinline__ u16 f2bf(float f) {
    unsigned int u = __builtin_bit_cast(unsigned int, f);
    u += 0x7fffu + ((u >> 16) & 1u);        // round-to-nearest-even
    return (u16)(u >> 16);
}

// ---------------------------------------------------------------------------
// Packed-weight geometry (16B fragments of 8 bf16). frag (l, nt, s, lane)
// holds B[s*32 + (lane>>4)*8 + j][nt*16 + (lane&15)], j=0..7, zero-padded.
// This layout serves BOTH as B-operand (col=lane&15) and A-operand
// (row=lane&15) of mfma_16x16x32 — identical packing.
//   l : KHpad KSteps Ntiles  frag_base
//   0 :    0    2     33        0
//   1 :  544   19     16     4224
//   2 :  256   10      8    23680
//   3 :  128    6      4    28800
//   4 :   64    4      2    30336
//   5 :   32    3      1    30848
//   6 :   32    1      1    31040   total 31104 frags = 497664 B in d_ws
// ---------------------------------------------------------------------------
__constant__ int pk_base8[8] = {0, 4224, 23680, 28800, 30336, 30848, 31040, 31104};
__constant__ int pk_ks[7]    = {2, 19, 10, 6, 4, 3, 1};
__constant__ int pk_khp[7]   = {0, 544, 256, 128, 64, 32, 32};
__constant__ int pk_kact[7]  = {0, 516, 256, 128, 64, 32, 16};
__constant__ int pk_nact[7]  = {516, 256, 128, 64, 32, 16, 2};

struct WPtrs { const float* W[7]; };

__global__ void pack_weights(WPtrs wp, u16* __restrict__ out)
{
    const int f = blockIdx.x * blockDim.x + threadIdx.x;
    if (f >= 31104) return;
    int l = 0;
    while (l < 6 && f >= pk_base8[l + 1]) ++l;
    const int r    = f - pk_base8[l];
    const int lane = r & 63;
    const int t    = r >> 6;
    const int ks   = pk_ks[l];
    const int s    = t % ks;
    const int nt   = t / ks;
    const int n    = nt * 16 + (lane & 15);
    const int k0   = s * 32 + (lane >> 4) * 8;
    const int nact = pk_nact[l];
    const int khp  = pk_khp[l];
    const int kact = pk_kact[l];
    const float* W = wp.W[l];

    union { short8 v; u16 e[8]; } frag;
#pragma unroll
    for (int j = 0; j < 8; ++j) {
        const int k = k0 + j;
        float v = 0.0f;
        if (n < nact) {
            if (k < khp) {
                if (k < kact) v = W[k * nact + n];
            } else {
                const int xr = k - khp;
                if (xr < 37) v = W[(kact + xr) * nact + n];
            }
        }
        frag.e[j] = f2bf(v);
    }
    *(short8*)(out + (size_t)f * 8) = frag.v;
}

// ---------------------------------------------------------------------------
// One MLP layer, 2m x 8n wave mapping. Wave (mg = wave&1, ng = (wave>>1)&7)
// owns m-tile mg and n-tiles {ng, ng+8, ...} < NT. K is processed in chunks
// of CK: A-frags (activations, LDS) loaded once per chunk and reused across
// the wave's n-tiles; B-frags (weights, global/L1/L2) loaded per (nt, chunk).
// MFMA operands swapped: D[n,pt]: row n = (lane>>4)*4 + r, col pt = lane&15.
// Epilogue: one ds_write_b64 of 4 consecutive-n bf16 per (u, lane).
// ---------------------------------------------------------------------------
template<int KHP, int HSEG, int OSEG, int NT, int NACT, int LBASE,
         bool XIN, bool RELU, bool GOUT>
__device__ __forceinline__ void mlayer(const u16* __restrict__ wpack,
                                       const float* __restrict__ bias,
                                       u16* __restrict__ s_act,
                                       float* __restrict__ gout, int p0,
                                       int wave, int lane)
{
    constexpr int KHS  = KHP / 32;
    constexpr int KS   = KHS + (XIN ? 2 : 0);
    constexpr int UMAX = (NT + 7) / 8;
    constexpr int CK   = 5;
    const int lm = lane & 15;
    const int lq = lane >> 4;
    const int mg = wave & 1;           // m-tile owned by this wave
    const int ng = (wave >> 1) & 7;    // n-group (0..7; &7 informs range)

    if (NT < 8 && ng >= NT) return;    // idle waves still reach caller barrier

    const u16* arow = s_act + (mg * 16 + lm) * SROW + lq * 8;
    const u16* wl   = wpack + LBASE + lane * 8;

    f32x4 acc[UMAX];
#pragma unroll
    for (int u = 0; u < UMAX; ++u)
        acc[u] = (f32x4){0.f, 0.f, 0.f, 0.f};

#pragma unroll
    for (int kc = 0; kc < KS; kc += CK) {
        // ---- A cluster: load once per chunk, reused by all n-tiles ----
        short8 a[CK];
#pragma unroll
        for (int j = 0; j < CK; ++j) {
            const int s = kc + j;
            if (s < KS) {
                const int ab = (s < KHS) ? (HSEG + s * 32)
                                         : (XIN_OFF + (s - KHS) * 32);
                a[j] = *(const short8*)(arow + ab);
            }
        }
#pragma unroll
        for (int u = 0; u < UMAX; ++u) {
            const int nt = ng + 8 * u;
            if (nt < NT) {
                const u16* bp = wl + (size_t)(nt * KS + kc) * 512;
                short8 bf[CK];
#pragma unroll
                for (int j = 0; j < CK; ++j)
                    if (kc + j < KS)
                        bf[j] = *(const short8*)(bp + (size_t)j * 512);
#pragma unroll
                for (int j = 0; j < CK; ++j)
                    if (kc + j < KS)   // swapped operands: D[n, pt]
                        acc[u] = __builtin_amdgcn_mfma_f32_16x16x32_bf16(bf[j], a[j], acc[u], 0, 0, 0);
            }
        }
    }

    // ---- epilogue: lane lm = point, 4 consecutive n per lane ----
#pragma unroll
    for (int u = 0; u < UMAX; ++u) {
        const int nt = ng + 8 * u;
        if (nt >= NT) continue;
        const int bn = nt * 16 + lq * 4;
        float bv[4];
        if (bn + 4 <= NACT) {
            const f32x4 b4 = *(const f32x4*)(bias + bn);
            bv[0] = b4[0]; bv[1] = b4[1]; bv[2] = b4[2]; bv[3] = b4[3];
        } else {
#pragma unroll
            for (int r = 0; r < 4; ++r)
                bv[r] = (bn + r < NACT) ? bias[bn + r] : 0.f;
        }
        if (GOUT) {
            if (lq == 0) {             // only n=0,1 valid (NACT=2)
                float2 o;
                o.x = acc[u][0] + bv[0];
                o.y = acc[u][1] + bv[1];
                *(float2*)(gout + (size_t)(p0 + mg * 16 + lm) * 2) = o;
            }
        } else {
            short4v o;
#pragma unroll
            for (int r = 0; r < 4; ++r) {
                float v = acc[u][r] + bv[r];
                if (RELU) v = fmaxf(v, 0.f);
                o[r] = (short)f2bf(v);
            }
            *(short4v*)(s_act + (size_t)(mg * 16 + lm) * SROW + OSEG + bn) = o;
        }
    }
}

struct MainParams {
    const float* lr;     // [B,2,64,64]
    const float* ctx;    // [B,32,64,64]
    const float* eps;    // [B,64,64]
    const float* coord;  // [B,N,2]
    const float* Bb[7];  // biases (fp32)
    const u16*   wpack;  // packed bf16 weights in d_ws
    float*       out;    // [B,N,2]
};

__global__ __launch_bounds__(NTH, 8)   // 8 waves/EU = 32 waves/CU = 2 blocks
void cont_decoder_mfma(MainParams p)
{
    extern __shared__ u16 s_act[];         // MPTS*SROW bf16 = 55808 B
    __shared__ int   s_x0[MPTS], s_y0[MPTS];
    __shared__ float s_wx[MPTS], s_wy[MPTS];

    const int tid  = threadIdx.x;
    const int wave = tid >> 6;
    const int lane = tid & 63;
    const int p0   = blockIdx.x * MPTS;
    const int b    = p0 >> 14;             // 16384 points per batch

    // ---- zero pad regions: xin[37..64) and hA[528..544) (cols 592..608) ----
    for (int i = tid; i < MPTS * 43; i += NTH) {
        const int pt = i / 43, c = i % 43;
        const int col = (c < 27) ? (37 + c) : (592 + (c - 27));
        s_act[pt * SROW + col] = 0;
    }

    // ---- bilinear params + coord features ----
    if (tid < MPTS) {
        const int pt = p0 + tid;
        const float cx = p.coord[2 * pt];
        const float cy = p.coord[2 * pt + 1];
        const float gx = (cx + 1.0f) * 32.0f - 0.5f;   // align_corners=False
        const float gy = (cy + 1.0f) * 32.0f - 0.5f;
        const float fx0 = floorf(gx), fy0 = floorf(gy);
        s_x0[tid] = (int)fx0;
        s_y0[tid] = (int)fy0;
        s_wx[tid] = gx - fx0;
        s_wy[tid] = gy - fy0;
        s_act[tid * SROW + 32] = f2bf(cx);
        s_act[tid * SROW + 33] = f2bf(cy);
    }
    __syncthreads();

    // ---- sample 35 channels/point (ref swaps spatial axes: val = g[b,c,x,y]) ----
    for (int idx = tid; idx < MPTS * 35; idx += NTH) {
        const int t = idx / 35;
        const int c = idx % 35;
        const float* base;
        int col;
        if (c < 32)      { base = p.ctx + (size_t)(b * 32 + c) * 4096;       col = c; }
        else if (c < 34) { base = p.lr  + (size_t)(b * 2 + (c - 32)) * 4096; col = 34 + (c - 32); }
        else             { base = p.eps + (size_t)b * 4096;                   col = 36; }

        const int   x0 = s_x0[t], y0 = s_y0[t];
        const float wx = s_wx[t], wy = s_wy[t];
        const int x1 = x0 + 1, y1 = y0 + 1;
        const bool xv0 = (x0 >= 0) & (x0 < 64);
        const bool xv1 = (x1 >= 0) & (x1 < 64);
        const bool yv0 = (y0 >= 0) & (y0 < 64);
        const bool yv1 = (y1 >= 0) & (y1 < 64);
        const int xc0 = min(max(x0, 0), 63), xc1 = min(max(x1, 0), 63);
        const int yc0 = min(max(y0, 0), 63), yc1 = min(max(y1, 0), 63);

        const float w00 = (1.0f - wx) * (1.0f - wy) * ((xv0 && yv0) ? 1.0f : 0.0f);
        const float w10 = wx * (1.0f - wy)          * ((xv1 && yv0) ? 1.0f : 0.0f);
        const float w01 = (1.0f - wx) * wy          * ((xv0 && yv1) ? 1.0f : 0.0f);
        const float w11 = wx * wy                   * ((xv1 && yv1) ? 1.0f : 0.0f);

        const float val = w00 * base[xc0 * 64 + yc0]
                        + w10 * base[xc1 * 64 + yc0]
                        + w01 * base[xc0 * 64 + yc1]
                        + w11 * base[xc1 * 64 + yc1];
        s_act[t * SROW + col] = f2bf(val);
    }
    __syncthreads();

    // ---- MLP:  xin(37p64) ->W0-> hA(516p528) ->W1-> hB(256) ->W2-> hA(128)
    //            ->W3-> hB(64) ->W4-> hA(32) ->W5-> hB(16) ->W6-> out(2)
    //       KHP  HSEG    OSEG    NT  NACT LBASE(elems)  XIN   RELU   GOUT
    mlayer<  0,  HA_OFF, HA_OFF, 33, 516, 0,      true,  true,  false>(p.wpack, p.Bb[0], s_act, nullptr, p0, wave, lane);
    __syncthreads();
    mlayer<544,  HA_OFF, HB_OFF, 16, 256, 33792,  true,  true,  false>(p.wpack, p.Bb[1], s_act, nullptr, p0, wave, lane);
    __syncthreads();
    mlayer<256,  HB_OFF, HA_OFF,  8, 128, 189440, true,  true,  false>(p.wpack, p.Bb[2], s_act, nullptr, p0, wave, lane);
    __syncthreads();
    mlayer<128,  HA_OFF, HB_OFF,  4,  64, 230400, true,  true,  false>(p.wpack, p.Bb[3], s_act, nullptr, p0, wave, lane);
    __syncthreads();
    mlayer< 64,  HB_OFF, HA_OFF,  2,  32, 242688, true,  true,  false>(p.wpack, p.Bb[4], s_act, nullptr, p0, wave, lane);
    __syncthreads();
    mlayer< 32,  HA_OFF, HB_OFF,  1,  16, 246784, true,  true,  false>(p.wpack, p.Bb[5], s_act, nullptr, p0, wave, lane);
    __syncthreads();
    mlayer< 32,  HB_OFF, 0,       1,   2, 248320, false, false, true >(p.wpack, p.Bb[6], s_act, p.out,   p0, wave, lane);
}

extern "C" void kernel_launch(void* const* d_in, const int* in_sizes, int n_in,
                              void* d_out, int out_size, void* d_ws, size_t ws_size,
                              hipStream_t stream)
{
    WPtrs wp;
    for (int l = 0; l < 7; ++l) wp.W[l] = (const float*)d_in[4 + 2 * l];

    MainParams p;
    p.lr    = (const float*)d_in[0];
    p.ctx   = (const float*)d_in[1];
    p.eps   = (const float*)d_in[2];
    p.coord = (const float*)d_in[3];
    for (int l = 0; l < 7; ++l) p.Bb[l] = (const float*)d_in[5 + 2 * l];
    p.wpack = (const u16*)d_ws;
    p.out   = (float*)d_out;

    // Opt in to large dynamic LDS (idempotent; not a stream op, capture-safe).
    hipFuncSetAttribute((const void*)cont_decoder_mfma,
                        hipFuncAttributeMaxDynamicSharedMemorySize, LDSBYTES);

    hipLaunchKernelGGL(pack_weights, dim3(122), dim3(256), 0, stream, wp, (u16*)d_ws);
    hipLaunchKernelGGL(cont_decoder_mfma, dim3(GRIDX), dim3(NTH), LDSBYTES, stream, p);
}

// Round 5
// 231.099 us; speedup vs baseline: 1.1365x; 1.1365x over previous
//
#include <hip/hip_runtime.h>

// ============================================================================
// ContDecoder on MI355X — bf16 MFMA, round 7.
// MPTS=32, 1024 threads (16 waves), 55.8 KB dynamic LDS, 2 blocks/CU.
//
// Traffic triangle (waves = Wm x Wn): A-LDS ∝ Wn*KS*MTILES, B-L2 ∝ Wm*NT*KS.
//   round 4 = (1,16): L1 A=608, B=304, 16 waves  -> 147 us
//   round 6 = (2, 8): L1 A=304, B=608, 16 waves  -> 191 us (B via L2 doubled)
//   round 7 = (1, 8): L1 A=304, B=304,  8 waves  <- dominated corner
// Each wave owns BOTH m-tiles (MS=2) and UPW consecutive n-tiles: A-frags
// loaded once per k-step, reused across UPW n-tiles; B-frags loaded exactly
// once per block; 2*UPW independent MFMA chains per wave (ILP).
// Kept from round 6 (verified good): swapped operands mfma(W,X) -> D[n,pt],
// vectorized ds_write_b64 epilogue + float4 bias (conflicts -28%).
// Added: s_setprio(1) around MFMA cluster (T5; waves are role-diverse).
//
// LDS row layout per point (bf16): [xin 0..64 | hA 64..608 | hB 608..864],
// stride 872 elems. Stale bytes in reused regions are masked by zero-packed
// weight rows; pad neurons get bias 0 so they write exact zeros.
// ============================================================================

#define NTH     1024
#define NWAVES  16
#define MPTS    32              // points per block (2 m-tiles of 16)
#define MTILES  (MPTS / 16)
#define SROW    872             // LDS row stride in bf16 elems
#define XIN_OFF 0
#define HA_OFF  64
#define HB_OFF  608
#define NPOINTS (8 * 16384)
#define GRIDX   (NPOINTS / MPTS)   // 4096 blocks
#define LDSBYTES (MPTS * SROW * 2) // 55808 -> 2 blocks/CU

typedef short          short8  __attribute__((ext_vector_type(8)));
typedef short          short4v __attribute__((ext_vector_type(4)));
typedef float          f32x4   __attribute__((ext_vector_type(4)));
typedef unsigned short u16;

__device__ __forceinline__ u16 f2bf(float f) {
    unsigned int u = __builtin_bit_cast(unsigned int, f);
    u += 0x7fffu + ((u >> 16) & 1u);        // round-to-nearest-even
    return (u16)(u >> 16);
}

// ---------------------------------------------------------------------------
// Packed-weight geometry (16B fragments of 8 bf16). frag (l, nt, s, lane)
// holds B[s*32 + (lane>>4)*8 + j][nt*16 + (lane&15)], j=0..7, zero-padded.
// Identical byte layout as A- or B-operand of mfma_16x16x32 (HW-verified in
// round 6: swapped-operand kernel passed with same absmax).
//   l : KHpad KSteps Ntiles  frag_base
//   0 :    0    2     33        0
//   1 :  544   19     16     4224
//   2 :  256   10      8    23680
//   3 :  128    6      4    28800
//   4 :   64    4      2    30336
//   5 :   32    3      1    30848
//   6 :   32    1      1    31040   total 31104 frags = 497664 B in d_ws
// ---------------------------------------------------------------------------
__constant__ int pk_base8[8] = {0, 4224, 23680, 28800, 30336, 30848, 31040, 31104};
__constant__ int pk_ks[7]    = {2, 19, 10, 6, 4, 3, 1};
__constant__ int pk_khp[7]   = {0, 544, 256, 128, 64, 32, 32};
__constant__ int pk_kact[7]  = {0, 516, 256, 128, 64, 32, 16};
__constant__ int pk_nact[7]  = {516, 256, 128, 64, 32, 16, 2};

struct WPtrs { const float* W[7]; };

__global__ void pack_weights(WPtrs wp, u16* __restrict__ out)
{
    const int f = blockIdx.x * blockDim.x + threadIdx.x;
    if (f >= 31104) return;
    int l = 0;
    while (l < 6 && f >= pk_base8[l + 1]) ++l;
    const int r    = f - pk_base8[l];
    const int lane = r & 63;
    const int t    = r >> 6;
    const int ks   = pk_ks[l];
    const int s    = t % ks;
    const int nt   = t / ks;
    const int n    = nt * 16 + (lane & 15);
    const int k0   = s * 32 + (lane >> 4) * 8;
    const int nact = pk_nact[l];
    const int khp  = pk_khp[l];
    const int kact = pk_kact[l];
    const float* W = wp.W[l];

    union { short8 v; u16 e[8]; } frag;
#pragma unroll
    for (int j = 0; j < 8; ++j) {
        const int k = k0 + j;
        float v = 0.0f;
        if (n < nact) {
            if (k < khp) {
                if (k < kact) v = W[k * nact + n];
            } else {
                const int xr = k - khp;
                if (xr < 37) v = W[(kact + xr) * nact + n];
            }
        }
        frag.e[j] = f2bf(v);
    }
    *(short8*)(out + (size_t)f * 8) = frag.v;
}

// ---------------------------------------------------------------------------
// One MLP layer, (Wm=1, Wn) mapping. Wave w owns n-tiles [w*UPW, w*UPW+UPW)
// and ALL MTILES m-tiles. Per k-step: MS A-reads (LDS, shared across the
// wave's n-tiles) + UPW B-loads (global/L2, each frag read once per block)
// + MS*UPW MFMAs (swapped operands -> D[n, pt]).
// D layout: col pt = lane&15, row n = (lane>>4)*4 + r.
// Epilogue: one ds_write_b64 of 4 consecutive-n bf16 per (i, m, lane).
// ---------------------------------------------------------------------------
template<int KHP, int HSEG, int OSEG, int NT, int UPW, int NACT, int LBASE,
         bool XIN, bool RELU, bool GOUT>
__device__ __forceinline__ void mlayer(const u16* __restrict__ wpack,
                                       const float* __restrict__ bias,
                                       u16* __restrict__ s_act,
                                       float* __restrict__ gout, int p0,
                                       int wave, int lane)
{
    constexpr int KHS = KHP / 32;
    constexpr int KS  = KHS + (XIN ? 2 : 0);
    constexpr int MS  = MTILES;        // 2 m-tiles, all owned by each wave
    const int lm = lane & 15;
    const int lq = lane >> 4;

    const int n0 = wave * UPW;
    if (n0 >= NT) return;              // idle waves fall through to barrier

    const u16* arow[MS];
#pragma unroll
    for (int m = 0; m < MS; ++m)
        arow[m] = s_act + (m * 16 + lm) * SROW + lq * 8;
    const u16* wl = wpack + LBASE + lane * 8;

    f32x4 acc[UPW][MS];
#pragma unroll
    for (int i = 0; i < UPW; ++i)
#pragma unroll
        for (int m = 0; m < MS; ++m)
            acc[i][m] = (f32x4){0.f, 0.f, 0.f, 0.f};

#pragma unroll
    for (int s = 0; s < KS; ++s) {
        const int ab = (s < KHS) ? (HSEG + s * 32)
                                 : (XIN_OFF + (s - KHS) * 32);
        short8 a[MS];
#pragma unroll
        for (int m = 0; m < MS; ++m)
            a[m] = *(const short8*)(arow[m] + ab);

        short8 bfr[UPW];
#pragma unroll
        for (int i = 0; i < UPW; ++i)
            if (n0 + i < NT)
                bfr[i] = *(const short8*)(wl + (size_t)((n0 + i) * KS + s) * 512);

        __builtin_amdgcn_s_setprio(1);
#pragma unroll
        for (int i = 0; i < UPW; ++i)
            if (n0 + i < NT)
#pragma unroll
                for (int m = 0; m < MS; ++m)
                    acc[i][m] = __builtin_amdgcn_mfma_f32_16x16x32_bf16(bfr[i], a[m], acc[i][m], 0, 0, 0);
        __builtin_amdgcn_s_setprio(0);
    }

    // ---- epilogue: lane lm = point, 4 consecutive n per (lane, i) ----
#pragma unroll
    for (int i = 0; i < UPW; ++i) {
        const int nt = n0 + i;
        if (nt >= NT) continue;
        const int bn = nt * 16 + lq * 4;
        float bv[4];
        if (bn + 4 <= NACT) {
            const f32x4 b4 = *(const f32x4*)(bias + bn);
            bv[0] = b4[0]; bv[1] = b4[1]; bv[2] = b4[2]; bv[3] = b4[3];
        } else {
#pragma unroll
            for (int r = 0; r < 4; ++r)
                bv[r] = (bn + r < NACT) ? bias[bn + r] : 0.f;
        }
        if (GOUT) {
            if (lq == 0) {             // only n=0,1 valid (NACT=2)
#pragma unroll
                for (int m = 0; m < MS; ++m) {
                    float2 o;
                    o.x = acc[i][m][0] + bv[0];
                    o.y = acc[i][m][1] + bv[1];
                    *(float2*)(gout + (size_t)(p0 + m * 16 + lm) * 2) = o;
                }
            }
        } else {
#pragma unroll
            for (int m = 0; m < MS; ++m) {
                short4v o;
#pragma unroll
                for (int r = 0; r < 4; ++r) {
                    float v = acc[i][m][r] + bv[r];
                    if (RELU) v = fmaxf(v, 0.f);
                    o[r] = (short)f2bf(v);
                }
                *(short4v*)(s_act + (size_t)(m * 16 + lm) * SROW + OSEG + bn) = o;
            }
        }
    }
}

struct MainParams {
    const float* lr;     // [B,2,64,64]
    const float* ctx;    // [B,32,64,64]
    const float* eps;    // [B,64,64]
    const float* coord;  // [B,N,2]
    const float* Bb[7];  // biases (fp32)
    const u16*   wpack;  // packed bf16 weights in d_ws
    float*       out;    // [B,N,2]
};

__global__ __launch_bounds__(NTH, 8)   // 8 waves/EU = 32 waves/CU = 2 blocks
void cont_decoder_mfma(MainParams p)
{
    extern __shared__ u16 s_act[];         // MPTS*SROW bf16 = 55808 B
    __shared__ int   s_x0[MPTS], s_y0[MPTS];
    __shared__ float s_wx[MPTS], s_wy[MPTS];

    const int tid  = threadIdx.x;
    const int wave = tid >> 6;
    const int lane = tid & 63;
    const int p0   = blockIdx.x * MPTS;
    const int b    = p0 >> 14;             // 16384 points per batch

    // ---- zero pad regions: xin[37..64) and hA[528..544) (cols 592..608) ----
    for (int i = tid; i < MPTS * 43; i += NTH) {
        const int pt = i / 43, c = i % 43;
        const int col = (c < 27) ? (37 + c) : (592 + (c - 27));
        s_act[pt * SROW + col] = 0;
    }

    // ---- bilinear params + coord features ----
    if (tid < MPTS) {
        const int pt = p0 + tid;
        const float cx = p.coord[2 * pt];
        const float cy = p.coord[2 * pt + 1];
        const float gx = (cx + 1.0f) * 32.0f - 0.5f;   // align_corners=False
        const float gy = (cy + 1.0f) * 32.0f - 0.5f;
        const float fx0 = floorf(gx), fy0 = floorf(gy);
        s_x0[tid] = (int)fx0;
        s_y0[tid] = (int)fy0;
        s_wx[tid] = gx - fx0;
        s_wy[tid] = gy - fy0;
        s_act[tid * SROW + 32] = f2bf(cx);
        s_act[tid * SROW + 33] = f2bf(cy);
    }
    __syncthreads();

    // ---- sample 35 channels/point (ref swaps spatial axes: val = g[b,c,x,y]) ----
    for (int idx = tid; idx < MPTS * 35; idx += NTH) {
        const int t = idx / 35;
        const int c = idx % 35;
        const float* base;
        int col;
        if (c < 32)      { base = p.ctx + (size_t)(b * 32 + c) * 4096;       col = c; }
        else if (c < 34) { base = p.lr  + (size_t)(b * 2 + (c - 32)) * 4096; col = 34 + (c - 32); }
        else             { base = p.eps + (size_t)b * 4096;                   col = 36; }

        const int   x0 = s_x0[t], y0 = s_y0[t];
        const float wx = s_wx[t], wy = s_wy[t];
        const int x1 = x0 + 1, y1 = y0 + 1;
        const bool xv0 = (x0 >= 0) & (x0 < 64);
        const bool xv1 = (x1 >= 0) & (x1 < 64);
        const bool yv0 = (y0 >= 0) & (y0 < 64);
        const bool yv1 = (y1 >= 0) & (y1 < 64);
        const int xc0 = min(max(x0, 0), 63), xc1 = min(max(x1, 0), 63);
        const int yc0 = min(max(y0, 0), 63), yc1 = min(max(y1, 0), 63);

        const float w00 = (1.0f - wx) * (1.0f - wy) * ((xv0 && yv0) ? 1.0f : 0.0f);
        const float w10 = wx * (1.0f - wy)          * ((xv1 && yv0) ? 1.0f : 0.0f);
        const float w01 = (1.0f - wx) * wy          * ((xv0 && yv1) ? 1.0f : 0.0f);
        const float w11 = wx * wy                   * ((xv1 && yv1) ? 1.0f : 0.0f);

        const float val = w00 * base[xc0 * 64 + yc0]
                        + w10 * base[xc1 * 64 + yc0]
                        + w01 * base[xc0 * 64 + yc1]
                        + w11 * base[xc1 * 64 + yc1];
        s_act[t * SROW + col] = f2bf(val);
    }
    __syncthreads();

    // ---- MLP:  xin(37p64) ->W0-> hA(516p528) ->W1-> hB(256) ->W2-> hA(128)
    //            ->W3-> hB(64) ->W4-> hA(32) ->W5-> hB(16) ->W6-> out(2)
    // UPW per layer: L0=3 (11 waves, A-reuse x3), L1=2 (8 waves, A-reuse x2),
    // L2..L6=1 (same parallelism as round 4).
    //       KHP  HSEG    OSEG    NT UPW NACT LBASE(elems)  XIN   RELU   GOUT
    mlayer<  0,  HA_OFF, HA_OFF, 33, 3, 516, 0,      true,  true,  false>(p.wpack, p.Bb[0], s_act, nullptr, p0, wave, lane);
    __syncthreads();
    mlayer<544,  HA_OFF, HB_OFF, 16, 2, 256, 33792,  true,  true,  false>(p.wpack, p.Bb[1], s_act, nullptr, p0, wave, lane);
    __syncthreads();
    mlayer<256,  HB_OFF, HA_OFF,  8, 1, 128, 189440, true,  true,  false>(p.wpack, p.Bb[2], s_act, nullptr, p0, wave, lane);
    __syncthreads();
    mlayer<128,  HA_OFF, HB_OFF,  4, 1,  64, 230400, true,  true,  false>(p.wpack, p.Bb[3], s_act, nullptr, p0, wave, lane);
    __syncthreads();
    mlayer< 64,  HB_OFF, HA_OFF,  2, 1,  32, 242688, true,  true,  false>(p.wpack, p.Bb[4], s_act, nullptr, p0, wave, lane);
    __syncthreads();
    mlayer< 32,  HA_OFF, HB_OFF,  1, 1,  16, 246784, true,  true,  false>(p.wpack, p.Bb[5], s_act, nullptr, p0, wave, lane);
    __syncthreads();
    mlayer< 32,  HB_OFF, 0,       1, 1,   2, 248320, false, false, true >(p.wpack, p.Bb[6], s_act, p.out,   p0, wave, lane);
}

extern "C" void kernel_launch(void* const* d_in, const int* in_sizes, int n_in,
                              void* d_out, int out_size, void* d_ws, size_t ws_size,
                              hipStream_t stream)
{
    WPtrs wp;
    for (int l = 0; l < 7; ++l) wp.W[l] = (const float*)d_in[4 + 2 * l];

    MainParams p;
    p.lr    = (const float*)d_in[0];
    p.ctx   = (const float*)d_in[1];
    p.eps   = (const float*)d_in[2];
    p.coord = (const float*)d_in[3];
    for (int l = 0; l < 7; ++l) p.Bb[l] = (const float*)d_in[5 + 2 * l];
    p.wpack = (const u16*)d_ws;
    p.out   = (float*)d_out;

    // Opt in to large dynamic LDS (idempotent; not a stream op, capture-safe).
    hipFuncSetAttribute((const void*)cont_decoder_mfma,
                        hipFuncAttributeMaxDynamicSharedMemorySize, LDSBYTES);

    hipLaunchKernelGGL(pack_weights, dim3(122), dim3(256), 0, stream, wp, (u16*)d_ws);
    hipLaunchKernelGGL(cont_decoder_mfma, dim3(GRIDX), dim3(NTH), LDSBYTES, stream, p);
}

// Round 6
// 220.793 us; speedup vs baseline: 1.1896x; 1.0467x over previous
//
#include <hip/hip_runtime.h>

// ============================================================================
// ContDecoder on MI355X — bf16 MFMA, round 8.
// MPTS=32, 1024 threads (16 waves), 55.8 KB dynamic LDS, 2 blocks/CU.
//
// Evidence through r7: latency-bound + TLP-starved. r4's full-16-wave
// mapping (147us) beats all traffic-reduction variants (r6 191, r7 159);
// compiler flattens every source-level pipeline to ~1 load in flight
// (VGPR 28-32 across r5/r6/r7). Round-8:
//   - r4 mapping restored: wave strides n-tiles (nt += 16), MS=2 m-tiles,
//     all 16 waves active on every big layer.
//   - kept from r6/r7 (verified): swapped operands mfma(W,X) -> D[n,pt],
//     ds_write_b64 epilogue + float4 bias (bank conflicts -28%).
//   - NEW: sched_group_barrier directive stream per unit forcing 2-K-step
//     load lookahead: {ds2,vm1}x2 prologue, then per step {mfma2, ds2,vm1}.
//     Compile-time schedule the compiler must honor -> loads stay in flight.
//   - setprio removed (unproven here; m190 negative on lockstep structures).
//
// LDS row layout per point (bf16): [xin 0..64 | hA 64..608 | hB 608..864],
// stride 872 elems. Stale bytes in reused regions are masked by zero-packed
// weight rows; pad neurons get bias 0 so they write exact zeros.
// ============================================================================

#define NTH     1024
#define NWAVES  16
#define MPTS    32              // points per block (2 m-tiles of 16)
#define MTILES  (MPTS / 16)
#define SROW    872             // LDS row stride in bf16 elems
#define XIN_OFF 0
#define HA_OFF  64
#define HB_OFF  608
#define NPOINTS (8 * 16384)
#define GRIDX   (NPOINTS / MPTS)   // 4096 blocks
#define LDSBYTES (MPTS * SROW * 2) // 55808 -> 2 blocks/CU

// sched_group_barrier masks (LLVM SchedGroupMask)
#define SGB __builtin_amdgcn_sched_group_barrier
#define SG_MFMA   0x008
#define SG_VMREAD 0x020
#define SG_DSREAD 0x100

typedef short          short8  __attribute__((ext_vector_type(8)));
typedef short          short4v __attribute__((ext_vector_type(4)));
typedef float          f32x4   __attribute__((ext_vector_type(4)));
typedef unsigned short u16;

__device__ __forceinline__ u16 f2bf(float f) {
    unsigned int u = __builtin_bit_cast(unsigned int, f);
    u += 0x7fffu + ((u >> 16) & 1u);        // round-to-nearest-even
    return (u16)(u >> 16);
}

// ---------------------------------------------------------------------------
// Packed-weight geometry (16B fragments of 8 bf16). frag (l, nt, s, lane)
// holds B[s*32 + (lane>>4)*8 + j][nt*16 + (lane&15)], j=0..7, zero-padded.
// Identical byte layout as A- or B-operand of mfma_16x16x32 (HW-verified:
// swapped-operand kernels r6/r7 passed with same absmax).
//   l : KHpad KSteps Ntiles  frag_base
//   0 :    0    2     33        0
//   1 :  544   19     16     4224
//   2 :  256   10      8    23680
//   3 :  128    6      4    28800
//   4 :   64    4      2    30336
//   5 :   32    3      1    30848
//   6 :   32    1      1    31040   total 31104 frags = 497664 B in d_ws
// ---------------------------------------------------------------------------
__constant__ int pk_base8[8] = {0, 4224, 23680, 28800, 30336, 30848, 31040, 31104};
__constant__ int pk_ks[7]    = {2, 19, 10, 6, 4, 3, 1};
__constant__ int pk_khp[7]   = {0, 544, 256, 128, 64, 32, 32};
__constant__ int pk_kact[7]  = {0, 516, 256, 128, 64, 32, 16};
__constant__ int pk_nact[7]  = {516, 256, 128, 64, 32, 16, 2};

struct WPtrs { const float* W[7]; };

__global__ void pack_weights(WPtrs wp, u16* __restrict__ out)
{
    const int f = blockIdx.x * blockDim.x + threadIdx.x;
    if (f >= 31104) return;
    int l = 0;
    while (l < 6 && f >= pk_base8[l + 1]) ++l;
    const int r    = f - pk_base8[l];
    const int lane = r & 63;
    const int t    = r >> 6;
    const int ks   = pk_ks[l];
    const int s    = t % ks;
    const int nt   = t / ks;
    const int n    = nt * 16 + (lane & 15);
    const int k0   = s * 32 + (lane >> 4) * 8;
    const int nact = pk_nact[l];
    const int khp  = pk_khp[l];
    const int kact = pk_kact[l];
    const float* W = wp.W[l];

    union { short8 v; u16 e[8]; } frag;
#pragma unroll
    for (int j = 0; j < 8; ++j) {
        const int k = k0 + j;
        float v = 0.0f;
        if (n < nact) {
            if (k < khp) {
                if (k < kact) v = W[k * nact + n];
            } else {
                const int xr = k - khp;
                if (xr < 37) v = W[(kact + xr) * nact + n];
            }
        }
        frag.e[j] = f2bf(v);
    }
    *(short8*)(out + (size_t)f * 8) = frag.v;
}

// ---------------------------------------------------------------------------
// One MLP layer, r4 mapping: wave w handles n-tiles {w, w+16, ...} < NT,
// both m-tiles each (MS=2). Per K-step: 2 ds_read_b128 (A) + 1
// global_load_dwordx4 (B, L2-resident pack) + 2 MFMA (swapped: D[n,pt]).
// SGB stream forces 2-step load lookahead in the emitted schedule.
// D layout: col pt = lane&15, row n = (lane>>4)*4 + r.
// ---------------------------------------------------------------------------
template<int KHP, int HSEG, int OSEG, int NT, int NACT, int LBASE,
         bool XIN, bool RELU, bool GOUT>
__device__ __forceinline__ void mlayer(const u16* __restrict__ wpack,
                                       const float* __restrict__ bias,
                                       u16* __restrict__ s_act,
                                       float* __restrict__ gout, int p0,
                                       int wave, int lane)
{
    constexpr int KHS = KHP / 32;
    constexpr int KS  = KHS + (XIN ? 2 : 0);
    constexpr int MS  = MTILES;        // 2 m-tiles, both owned by each wave
    const int lm = lane & 15;
    const int lq = lane >> 4;
    const u16* wl = wpack + LBASE + lane * 8;

    const u16* arow[MS];
#pragma unroll
    for (int m = 0; m < MS; ++m)
        arow[m] = s_act + (m * 16 + lm) * SROW + lq * 8;

    for (int nt = wave; nt < NT; nt += NWAVES) {
        const u16* bp = wl + (size_t)nt * KS * 512;

        f32x4 acc[MS];
#pragma unroll
        for (int m = 0; m < MS; ++m)
            acc[m] = (f32x4){0.f, 0.f, 0.f, 0.f};

#pragma unroll
        for (int s = 0; s < KS; ++s) {
            const int ab = (s < KHS) ? (HSEG + s * 32)
                                     : (XIN_OFF + (s - KHS) * 32);
            short8 a[MS];
#pragma unroll
            for (int m = 0; m < MS; ++m)
                a[m] = *(const short8*)(arow[m] + ab);
            const short8 b = *(const short8*)(bp + (size_t)s * 512);
#pragma unroll
            for (int m = 0; m < MS; ++m)
                acc[m] = __builtin_amdgcn_mfma_f32_16x16x32_bf16(b, a[m], acc[m], 0, 0, 0);
        }

        // ---- schedule directive stream: 2-K-step load lookahead ----
        // prologue: loads of steps 0,1 first
        SGB(SG_DSREAD, 2, 0); SGB(SG_VMREAD, 1, 0);
        if (KS > 1) { SGB(SG_DSREAD, 2, 0); SGB(SG_VMREAD, 1, 0); }
#pragma unroll
        for (int s = 0; s < KS; ++s) {
            SGB(SG_MFMA, 2, 0);                       // mfma pair of step s
            if (s + 2 < KS) { SGB(SG_DSREAD, 2, 0); SGB(SG_VMREAD, 1, 0); }
        }

        // ---- epilogue: lane lm = point, 4 consecutive n per lane ----
        const int bn = nt * 16 + lq * 4;
        float bv[4];
        if (bn + 4 <= NACT) {
            const f32x4 b4 = *(const f32x4*)(bias + bn);
            bv[0] = b4[0]; bv[1] = b4[1]; bv[2] = b4[2]; bv[3] = b4[3];
        } else {
#pragma unroll
            for (int r = 0; r < 4; ++r)
                bv[r] = (bn + r < NACT) ? bias[bn + r] : 0.f;
        }
        if (GOUT) {
            if (lq == 0) {             // only n=0,1 valid (NACT=2)
#pragma unroll
                for (int m = 0; m < MS; ++m) {
                    float2 o;
                    o.x = acc[m][0] + bv[0];
                    o.y = acc[m][1] + bv[1];
                    *(float2*)(gout + (size_t)(p0 + m * 16 + lm) * 2) = o;
                }
            }
        } else {
#pragma unroll
            for (int m = 0; m < MS; ++m) {
                short4v o;
#pragma unroll
                for (int r = 0; r < 4; ++r) {
                    float v = acc[m][r] + bv[r];
                    if (RELU) v = fmaxf(v, 0.f);
                    o[r] = (short)f2bf(v);
                }
                *(short4v*)(s_act + (size_t)(m * 16 + lm) * SROW + OSEG + bn) = o;
            }
        }
    }
}

struct MainParams {
    const float* lr;     // [B,2,64,64]
    const float* ctx;    // [B,32,64,64]
    const float* eps;    // [B,64,64]
    const float* coord;  // [B,N,2]
    const float* Bb[7];  // biases (fp32)
    const u16*   wpack;  // packed bf16 weights in d_ws
    float*       out;    // [B,N,2]
};

__global__ __launch_bounds__(NTH, 8)   // 8 waves/EU = 32 waves/CU = 2 blocks
void cont_decoder_mfma(MainParams p)
{
    extern __shared__ u16 s_act[];         // MPTS*SROW bf16 = 55808 B
    __shared__ int   s_x0[MPTS], s_y0[MPTS];
    __shared__ float s_wx[MPTS], s_wy[MPTS];

    const int tid  = threadIdx.x;
    const int wave = tid >> 6;
    const int lane = tid & 63;
    const int p0   = blockIdx.x * MPTS;
    const int b    = p0 >> 14;             // 16384 points per batch

    // ---- zero pad regions: xin[37..64) and hA[528..544) (cols 592..608) ----
    for (int i = tid; i < MPTS * 43; i += NTH) {
        const int pt = i / 43, c = i % 43;
        const int col = (c < 27) ? (37 + c) : (592 + (c - 27));
        s_act[pt * SROW + col] = 0;
    }

    // ---- bilinear params + coord features ----
    if (tid < MPTS) {
        const int pt = p0 + tid;
        const float cx = p.coord[2 * pt];
        const float cy = p.coord[2 * pt + 1];
        const float gx = (cx + 1.0f) * 32.0f - 0.5f;   // align_corners=False
        const float gy = (cy + 1.0f) * 32.0f - 0.5f;
        const float fx0 = floorf(gx), fy0 = floorf(gy);
        s_x0[tid] = (int)fx0;
        s_y0[tid] = (int)fy0;
        s_wx[tid] = gx - fx0;
        s_wy[tid] = gy - fy0;
        s_act[tid * SROW + 32] = f2bf(cx);
        s_act[tid * SROW + 33] = f2bf(cy);
    }
    __syncthreads();

    // ---- sample 35 channels/point (ref swaps spatial axes: val = g[b,c,x,y]) ----
    for (int idx = tid; idx < MPTS * 35; idx += NTH) {
        const int t = idx / 35;
        const int c = idx % 35;
        const float* base;
        int col;
        if (c < 32)      { base = p.ctx + (size_t)(b * 32 + c) * 4096;       col = c; }
        else if (c < 34) { base = p.lr  + (size_t)(b * 2 + (c - 32)) * 4096; col = 34 + (c - 32); }
        else             { base = p.eps + (size_t)b * 4096;                   col = 36; }

        const int   x0 = s_x0[t], y0 = s_y0[t];
        const float wx = s_wx[t], wy = s_wy[t];
        const int x1 = x0 + 1, y1 = y0 + 1;
        const bool xv0 = (x0 >= 0) & (x0 < 64);
        const bool xv1 = (x1 >= 0) & (x1 < 64);
        const bool yv0 = (y0 >= 0) & (y0 < 64);
        const bool yv1 = (y1 >= 0) & (y1 < 64);
        const int xc0 = min(max(x0, 0), 63), xc1 = min(max(x1, 0), 63);
        const int yc0 = min(max(y0, 0), 63), yc1 = min(max(y1, 0), 63);

        const float w00 = (1.0f - wx) * (1.0f - wy) * ((xv0 && yv0) ? 1.0f : 0.0f);
        const float w10 = wx * (1.0f - wy)          * ((xv1 && yv0) ? 1.0f : 0.0f);
        const float w01 = (1.0f - wx) * wy          * ((xv0 && yv1) ? 1.0f : 0.0f);
        const float w11 = wx * wy                   * ((xv1 && yv1) ? 1.0f : 0.0f);

        const float val = w00 * base[xc0 * 64 + yc0]
                        + w10 * base[xc1 * 64 + yc0]
                        + w01 * base[xc0 * 64 + yc1]
                        + w11 * base[xc1 * 64 + yc1];
        s_act[t * SROW + col] = f2bf(val);
    }
    __syncthreads();

    // ---- MLP:  xin(37p64) ->W0-> hA(516p528) ->W1-> hB(256) ->W2-> hA(128)
    //            ->W3-> hB(64) ->W4-> hA(32) ->W5-> hB(16) ->W6-> out(2)
    //       KHP  HSEG    OSEG    NT  NACT LBASE(elems)  XIN   RELU   GOUT
    mlayer<  0,  HA_OFF, HA_OFF, 33, 516, 0,      true,  true,  false>(p.wpack, p.Bb[0], s_act, nullptr, p0, wave, lane);
    __syncthreads();
    mlayer<544,  HA_OFF, HB_OFF, 16, 256, 33792,  true,  true,  false>(p.wpack, p.Bb[1], s_act, nullptr, p0, wave, lane);
    __syncthreads();
    mlayer<256,  HB_OFF, HA_OFF,  8, 128, 189440, true,  true,  false>(p.wpack, p.Bb[2], s_act, nullptr, p0, wave, lane);
    __syncthreads();
    mlayer<128,  HA_OFF, HB_OFF,  4,  64, 230400, true,  true,  false>(p.wpack, p.Bb[3], s_act, nullptr, p0, wave, lane);
    __syncthreads();
    mlayer< 64,  HB_OFF, HA_OFF,  2,  32, 242688, true,  true,  false>(p.wpack, p.Bb[4], s_act, nullptr, p0, wave, lane);
    __syncthreads();
    mlayer< 32,  HA_OFF, HB_OFF,  1,  16, 246784, true,  true,  false>(p.wpack, p.Bb[5], s_act, nullptr, p0, wave, lane);
    __syncthreads();
    mlayer< 32,  HB_OFF, 0,       1,   2, 248320, false, false, true >(p.wpack, p.Bb[6], s_act, p.out,   p0, wave, lane);
}

extern "C" void kernel_launch(void* const* d_in, const int* in_sizes, int n_in,
                              void* d_out, int out_size, void* d_ws, size_t ws_size,
                              hipStream_t stream)
{
    WPtrs wp;
    for (int l = 0; l < 7; ++l) wp.W[l] = (const float*)d_in[4 + 2 * l];

    MainParams p;
    p.lr    = (const float*)d_in[0];
    p.ctx   = (const float*)d_in[1];
    p.eps   = (const float*)d_in[2];
    p.coord = (const float*)d_in[3];
    for (int l = 0; l < 7; ++l) p.Bb[l] = (const float*)d_in[5 + 2 * l];
    p.wpack = (const u16*)d_ws;
    p.out   = (float*)d_out;

    // Opt in to large dynamic LDS (idempotent; not a stream op, capture-safe).
    hipFuncSetAttribute((const void*)cont_decoder_mfma,
                        hipFuncAttributeMaxDynamicSharedMemorySize, LDSBYTES);

    hipLaunchKernelGGL(pack_weights, dim3(122), dim3(256), 0, stream, wp, (u16*)d_ws);
    hipLaunchKernelGGL(cont_decoder_mfma, dim3(GRIDX), dim3(NTH), LDSBYTES, stream, p);
}